// Round 7
// baseline (451.794 us; speedup 1.0000x reference)
//
#include <hip/hip_runtime.h>
#include <hip/hip_bf16.h>

#define HID 64
#define N_LAYERS 3
#define N_GRAPHS 64
#define N_CLASSES 5

// ---------------------------------------------------------------------------
// h0 = x @ node_W + node_b       [N,64]    (one wave per node, lane=channel)
// ---------------------------------------------------------------------------
__global__ __launch_bounds__(256) void node_embed_kernel(
    const float* __restrict__ x, const float* __restrict__ W,
    const float* __restrict__ b, float* __restrict__ h, int N)
{
    int tid = blockIdx.x * 256 + threadIdx.x;
    int n = tid >> 6;
    int c = tid & 63;
    if (n >= N) return;
    const float* xr = x + (size_t)n * 5;
    float acc = b[c];
#pragma unroll
    for (int k = 0; k < 5; ++k) acc = fmaf(xr[k], W[k * 64 + c], acc);
    h[(size_t)n * 64 + c] = acc;
}

// ---------------------------------------------------------------------------
// Wc[l] = edge_W @ lin_W[l]   [5,64];  bc[l] = edge_b @ lin_W[l] + lin_b[l]
// ---------------------------------------------------------------------------
__global__ __launch_bounds__(384) void combine_weights_kernel(
    const float* __restrict__ edge_W, const float* __restrict__ edge_b,
    const float* __restrict__ lin_W, const float* __restrict__ lin_b,
    float* __restrict__ Wc, float* __restrict__ bc)
{
    int l = blockIdx.x;
    int c = threadIdx.x & 63;
    int k = threadIdx.x >> 6;
    const float* LW = lin_W + (size_t)l * 64 * 64;
    if (k < 5) {
        float acc = 0.f;
        for (int j = 0; j < 64; ++j) acc = fmaf(edge_W[k * 64 + j], LW[j * 64 + c], acc);
        Wc[l * 320 + k * 64 + c] = acc;
    } else {
        float acc = lin_b[l * 64 + c];
        for (int j = 0; j < 64; ++j) acc = fmaf(edge_b[j], LW[j * 64 + c], acc);
        bc[l * 64 + c] = acc;
    }
}

// ===========================================================================
// CSR build (once per call): histogram -> block scan -> index scatter
// ===========================================================================
__global__ __launch_bounds__(256) void hist_kernel(
    const int* __restrict__ ei, int* __restrict__ deg, int E)
{
    int e = blockIdx.x * 256 + threadIdx.x;
    if (e < E) atomicAdd(&deg[ei[E + e]], 1);
}

// per-block sums of deg
__global__ __launch_bounds__(256) void scan1_kernel(
    const int* __restrict__ deg, int* __restrict__ bsum, int N)
{
    __shared__ int s[256];
    int t = threadIdx.x;
    int i = blockIdx.x * 256 + t;
    int v = (i < N) ? deg[i] : 0;
    s[t] = v; __syncthreads();
    for (int off = 128; off > 0; off >>= 1) {
        if (t < off) s[t] += s[t + off];
        __syncthreads();
    }
    if (t == 0) bsum[blockIdx.x] = s[0];
}

// exclusive scan of block sums (NBLK <= 256, single block)
__global__ __launch_bounds__(256) void scan2_kernel(
    const int* __restrict__ bsum, int* __restrict__ bpre, int NBLK)
{
    __shared__ int s[256];
    int t = threadIdx.x;
    int v = (t < NBLK) ? bsum[t] : 0;
    s[t] = v; __syncthreads();
    for (int off = 1; off < 256; off <<= 1) {
        int x = (t >= off) ? s[t - off] : 0;
        __syncthreads();
        s[t] += x;
        __syncthreads();
    }
    if (t < NBLK) bpre[t] = s[t] - v;
}

// per-block exclusive scan + block prefix -> rowptr
__global__ __launch_bounds__(256) void scan3_kernel(
    const int* __restrict__ deg, const int* __restrict__ bpre,
    int* __restrict__ rowptr, int N, int E)
{
    __shared__ int s[256];
    int t = threadIdx.x;
    int i = blockIdx.x * 256 + t;
    int v = (i < N) ? deg[i] : 0;
    s[t] = v; __syncthreads();
    for (int off = 1; off < 256; off <<= 1) {
        int x = (t >= off) ? s[t - off] : 0;
        __syncthreads();
        s[t] += x;
        __syncthreads();
    }
    if (i < N) rowptr[i] = bpre[blockIdx.x] + s[t] - v;
    if (i == N - 1) rowptr[N] = E;
}

// Linear attr pack (coalesced, edge order) + 8B {src,e} scatter to CSR pos.
// Random-write payload drops 36B -> 8B per edge (6.4MB array, L2-resident).
__global__ __launch_bounds__(256) void scatter_kernel(
    const int* __restrict__ ei, const float* __restrict__ ea,
    int* __restrict__ cursor, float* __restrict__ packed,
    int2* __restrict__ spos, int E)
{
    int e = blockIdx.x * 256 + threadIdx.x;
    if (e >= E) return;
    int src = ei[e];
    int dst = ei[E + e];
    const float* p = ea + (size_t)e * 5;
    // linear, coalesced 32B record in EDGE order
    float4 r0 = make_float4(p[0], p[1], p[2], p[3]);
    float4 r1 = make_float4(p[4], 0.f, 0.f, 0.f);
    float4* q = reinterpret_cast<float4*>(packed + (size_t)e * 8);
    q[0] = r0;
    q[1] = r1;
    // tiny random scatter: CSR position -> {src, edge id}
    int pos = atomicAdd(&cursor[dst], 1);
    spos[pos] = make_int2(src, e);
}

// ---------------------------------------------------------------------------
// Atomic-free aggregation: wave per node, lane = channel.
// One coalesced int2 load per <=64-edge chunk gives {src,e}; both broadcast
// via __shfl -> h-gathers AND attr-broadcast loads have register-resident
// addresses (no load->address dependence inside the chunk).
// agg[n] = sum_{e in CSR(n)} relu(h[src_e] + ea_e @ Wc + bc)
// ---------------------------------------------------------------------------
__global__ __launch_bounds__(256) void agg_kernel(
    const int* __restrict__ rowptr, const int2* __restrict__ spos,
    const float* __restrict__ packed,
    const float* __restrict__ h, const float* __restrict__ Wc,
    const float* __restrict__ bc, float* __restrict__ agg, int N)
{
    int lane = threadIdx.x & 63;
    float w0 = Wc[0 * 64 + lane];
    float w1 = Wc[1 * 64 + lane];
    float w2 = Wc[2 * 64 + lane];
    float w3 = Wc[3 * 64 + lane];
    float w4 = Wc[4 * 64 + lane];
    float bb = bc[lane];

    int wid = (blockIdx.x * 256 + threadIdx.x) >> 6;
    int nw  = (gridDim.x * 256) >> 6;
    for (int n = wid; n < N; n += nw) {
        int eb = rowptr[n];
        int ee = rowptr[n + 1];
        float acc = 0.f;
        for (int base = eb; base < ee; base += 64) {
            int cnt = min(64, ee - base);
            // one coalesced load covers src+eid for the whole chunk
            int2 se = spos[base + min(lane, cnt - 1)];
            int j = 0;
            for (; j + 3 < cnt; j += 4) {
                int s0 = __shfl(se.x, j + 0);
                int s1 = __shfl(se.x, j + 1);
                int s2 = __shfl(se.x, j + 2);
                int s3 = __shfl(se.x, j + 3);
                int e0 = __shfl(se.y, j + 0);
                int e1 = __shfl(se.y, j + 1);
                int e2 = __shfl(se.y, j + 2);
                int e3 = __shfl(se.y, j + 3);
                // gathers: addresses register-resident -> issue back-to-back
                float h0 = h[(size_t)s0 * 64 + lane];
                float h1 = h[(size_t)s1 * 64 + lane];
                float h2 = h[(size_t)s2 * 64 + lane];
                float h3 = h[(size_t)s3 * 64 + lane];
                // attr records: wave-broadcast 32B loads (single line each)
                const float4* q0 = reinterpret_cast<const float4*>(packed + (size_t)e0 * 8);
                const float4* q1 = reinterpret_cast<const float4*>(packed + (size_t)e1 * 8);
                const float4* q2 = reinterpret_cast<const float4*>(packed + (size_t)e2 * 8);
                const float4* q3 = reinterpret_cast<const float4*>(packed + (size_t)e3 * 8);
                float4 r0a = q0[0], r0b = q0[1];
                float4 r1a = q1[0], r1b = q1[1];
                float4 r2a = q2[0], r2b = q2[1];
                float4 r3a = q3[0], r3b = q3[1];
                float m0 = bb + h0;
                m0 = fmaf(r0a.x, w0, m0); m0 = fmaf(r0a.y, w1, m0);
                m0 = fmaf(r0a.z, w2, m0); m0 = fmaf(r0a.w, w3, m0);
                m0 = fmaf(r0b.x, w4, m0);
                float m1 = bb + h1;
                m1 = fmaf(r1a.x, w0, m1); m1 = fmaf(r1a.y, w1, m1);
                m1 = fmaf(r1a.z, w2, m1); m1 = fmaf(r1a.w, w3, m1);
                m1 = fmaf(r1b.x, w4, m1);
                float m2 = bb + h2;
                m2 = fmaf(r2a.x, w0, m2); m2 = fmaf(r2a.y, w1, m2);
                m2 = fmaf(r2a.z, w2, m2); m2 = fmaf(r2a.w, w3, m2);
                m2 = fmaf(r2b.x, w4, m2);
                float m3 = bb + h3;
                m3 = fmaf(r3a.x, w0, m3); m3 = fmaf(r3a.y, w1, m3);
                m3 = fmaf(r3a.z, w2, m3); m3 = fmaf(r3a.w, w3, m3);
                m3 = fmaf(r3b.x, w4, m3);
                acc += fmaxf(m0, 0.f);
                acc += fmaxf(m1, 0.f);
                acc += fmaxf(m2, 0.f);
                acc += fmaxf(m3, 0.f);
            }
            for (; j < cnt; ++j) {
                int s0 = __shfl(se.x, j);
                int e0 = __shfl(se.y, j);
                float h0 = h[(size_t)s0 * 64 + lane];
                const float4* q = reinterpret_cast<const float4*>(packed + (size_t)e0 * 8);
                float4 r0 = q[0];
                float4 r1 = q[1];
                float m = bb + h0;
                m = fmaf(r0.x, w0, m);
                m = fmaf(r0.y, w1, m);
                m = fmaf(r0.z, w2, m);
                m = fmaf(r0.w, w3, m);
                m = fmaf(r1.x, w4, m);
                acc += fmaxf(m, 0.f);
            }
        }
        agg[(size_t)n * 64 + lane] = acc;
    }
}

// ---------------------------------------------------------------------------
// Fallback (small ws): edge-parallel scatter with atomics
// ---------------------------------------------------------------------------
__global__ __launch_bounds__(256) void edge_kernel(
    const int* __restrict__ ei, const float* __restrict__ ea,
    const float* __restrict__ h, const float* __restrict__ Wc,
    const float* __restrict__ bc, float* __restrict__ agg, int E)
{
    int lane = threadIdx.x & 63;
    float w0 = Wc[0 * 64 + lane];
    float w1 = Wc[1 * 64 + lane];
    float w2 = Wc[2 * 64 + lane];
    float w3 = Wc[3 * 64 + lane];
    float w4 = Wc[4 * 64 + lane];
    float bb = bc[lane];

    int wave   = (blockIdx.x * 256 + threadIdx.x) >> 6;
    int nwaves = (gridDim.x * 256) >> 6;
    for (int e = wave; e < E; e += nwaves) {
        int src = ei[e];
        int dst = ei[E + e];
        const float* eap = ea + (size_t)e * 5;
        float m = bb + h[(size_t)src * 64 + lane];
        m = fmaf(eap[0], w0, m);
        m = fmaf(eap[1], w1, m);
        m = fmaf(eap[2], w2, m);
        m = fmaf(eap[3], w3, m);
        m = fmaf(eap[4], w4, m);
        m = fmaxf(m, 0.f);
        atomicAdd(&agg[(size_t)dst * 64 + lane], m);
    }
}

// ---------------------------------------------------------------------------
// Node update: z = h + agg; z = relu(z@W1+b1)@W2+b2; z = bn; h = relu(z)
// wave per node; W1/W2 columns in registers; in-place safe (own row only).
// ---------------------------------------------------------------------------
__global__ __launch_bounds__(256) void node_mlp_kernel(
    const float* __restrict__ h, const float* __restrict__ agg,
    const float* __restrict__ W1, const float* __restrict__ b1v,
    const float* __restrict__ W2, const float* __restrict__ b2v,
    const float* __restrict__ bng, const float* __restrict__ bnb,
    float* __restrict__ hout, int N)
{
    __shared__ float zbuf[4][64];
    int lane = threadIdx.x & 63;
    int w = threadIdx.x >> 6;

    float w1c[64], w2c[64];
#pragma unroll
    for (int k = 0; k < 64; ++k) w1c[k] = W1[k * 64 + lane];
#pragma unroll
    for (int k = 0; k < 64; ++k) w2c[k] = W2[k * 64 + lane];

    const float inv_std = 0.99999500003749981f; // 1/sqrt(1 + 1e-5)
    float bias1 = b1v[lane];
    float bias2 = b2v[lane];
    float scale = bng[lane] * inv_std;
    float shift = bnb[lane];

    int wid = blockIdx.x * 4 + w;
    int nw  = gridDim.x * 4;
    for (int n = wid; n < N; n += nw) {
        size_t off = (size_t)n * 64 + lane;
        float z = h[off] + agg[off];
        zbuf[w][lane] = z;
        float acc = bias1;
#pragma unroll
        for (int k4 = 0; k4 < 16; ++k4) {
            float4 zk = *reinterpret_cast<const float4*>(&zbuf[w][k4 * 4]);
            acc = fmaf(zk.x, w1c[k4 * 4 + 0], acc);
            acc = fmaf(zk.y, w1c[k4 * 4 + 1], acc);
            acc = fmaf(zk.z, w1c[k4 * 4 + 2], acc);
            acc = fmaf(zk.w, w1c[k4 * 4 + 3], acc);
        }
        float t = fmaxf(acc, 0.f);
        zbuf[w][lane] = t;
        float acc2 = bias2;
#pragma unroll
        for (int k4 = 0; k4 < 16; ++k4) {
            float4 tk = *reinterpret_cast<const float4*>(&zbuf[w][k4 * 4]);
            acc2 = fmaf(tk.x, w2c[k4 * 4 + 0], acc2);
            acc2 = fmaf(tk.y, w2c[k4 * 4 + 1], acc2);
            acc2 = fmaf(tk.z, w2c[k4 * 4 + 2], acc2);
            acc2 = fmaf(tk.w, w2c[k4 * 4 + 3], acc2);
        }
        float y = fmaf(acc2, scale, shift);
        hout[off] = fmaxf(y, 0.f);
    }
}

// ---------------------------------------------------------------------------
// Pooling: batch sorted -> per-wave contiguous chunk, flush on graph change.
// ---------------------------------------------------------------------------
__global__ __launch_bounds__(256) void pool_kernel(
    const float* __restrict__ h, const int* __restrict__ batch,
    float* __restrict__ psum, int* __restrict__ pmaxi, int* __restrict__ pcount, int N)
{
    int lane = threadIdx.x & 63;
    int chunks = gridDim.x * 4;
    int wid = blockIdx.x * 4 + (threadIdx.x >> 6);
    int CH = (N + chunks - 1) / chunks;
    int n0 = wid * CH;
    int n1 = min(N, n0 + CH);
    if (n0 >= n1) return;

    int gcur = batch[n0];
    float s = 0.f, mx = 0.f;
    int cnt = 0;
    for (int n = n0; n < n1; ++n) {
        int g = batch[n];
        if (g != gcur) {
            atomicAdd(&psum[gcur * 64 + lane], s);
            atomicMax(&pmaxi[gcur * 64 + lane], __float_as_int(mx));
            if (lane == 0) atomicAdd(&pcount[gcur], cnt);
            gcur = g; s = 0.f; mx = 0.f; cnt = 0;
        }
        float v = h[(size_t)n * 64 + lane];
        s += v;
        mx = fmaxf(mx, v);
        ++cnt;
    }
    atomicAdd(&psum[gcur * 64 + lane], s);
    atomicMax(&pmaxi[gcur * 64 + lane], __float_as_int(mx));
    if (lane == 0) atomicAdd(&pcount[gcur], cnt);
}

// ---------------------------------------------------------------------------
// Head: one block PER GRAPH (64 blocks).  hc=[mean,max,sum] (192 in LDS);
// 4 waves each cover a 48-wide K-slice of hc@W1; LDS reduce; wave 0 does
// relu + the 64x5 second GEMM.
// ---------------------------------------------------------------------------
__global__ __launch_bounds__(256) void head_kernel(
    const float* __restrict__ psum, const int* __restrict__ pmaxi,
    const int* __restrict__ pcount,
    const float* __restrict__ W1, const float* __restrict__ b1,
    const float* __restrict__ W2, const float* __restrict__ b2,
    float* __restrict__ out)
{
    __shared__ float hc[192];
    __shared__ float part[4][64];
    __shared__ float tbuf[64];
    int g = blockIdx.x;
    int tid = threadIdx.x;
    int lane = tid & 63;
    int w = tid >> 6;

    if (tid < 192) {
        int sec = tid >> 6;          // 0: mean, 1: max, 2: sum
        int c = tid & 63;
        float s = psum[g * 64 + c];
        float v;
        if (sec == 0) {
            int cn = pcount[g];
            v = s / fmaxf((float)cn, 1.f);
        } else if (sec == 1) {
            v = __int_as_float(pmaxi[g * 64 + c]);
        } else {
            v = s;
        }
        hc[sec * 64 + c] = v;
    }
    __syncthreads();

    float acc = (w == 0) ? b1[lane] : 0.f;
#pragma unroll
    for (int kk = 0; kk < 48; ++kk) {
        int k = w * 48 + kk;
        acc = fmaf(hc[k], W1[k * 64 + lane], acc);
    }
    part[w][lane] = acc;
    __syncthreads();

    if (w == 0) {
        float t = part[0][lane] + part[1][lane] + part[2][lane] + part[3][lane];
        t = fmaxf(t, 0.f);
        tbuf[lane] = t;                       // same-wave LDS: ordered, no barrier
        if (lane < N_CLASSES) {
            float o = b2[lane];
            for (int j = 0; j < 64; ++j) o = fmaf(tbuf[j], W2[j * N_CLASSES + lane], o);
            out[g * N_CLASSES + lane] = o;
        }
    }
}

// ---------------------------------------------------------------------------
extern "C" void kernel_launch(void* const* d_in, const int* in_sizes, int n_in,
                              void* d_out, int out_size, void* d_ws, size_t ws_size,
                              hipStream_t stream)
{
    const float* x         = (const float*)d_in[0];
    const float* edge_attr = (const float*)d_in[1];
    const int*   edge_index= (const int*)  d_in[2];
    const int*   batch     = (const int*)  d_in[3];
    const float* node_W    = (const float*)d_in[4];
    const float* node_b    = (const float*)d_in[5];
    const float* edge_W    = (const float*)d_in[6];
    const float* edge_b    = (const float*)d_in[7];
    const float* lin_W     = (const float*)d_in[8];
    const float* lin_b     = (const float*)d_in[9];
    const float* mlp_W1    = (const float*)d_in[10];
    const float* mlp_b1    = (const float*)d_in[11];
    const float* mlp_W2    = (const float*)d_in[12];
    const float* mlp_b2    = (const float*)d_in[13];
    const float* bn_g      = (const float*)d_in[14];
    const float* bn_b      = (const float*)d_in[15];
    const float* head_W1   = (const float*)d_in[16];
    const float* head_b1   = (const float*)d_in[17];
    const float* head_W2   = (const float*)d_in[18];
    const float* head_b2   = (const float*)d_in[19];
    float* out = (float*)d_out;

    const int N = in_sizes[0] / 5;        // 50000
    const int E = in_sizes[1] / 5;        // 800000
    const int NBLK = (N + 255) / 256;     // scan blocks (196 <= 256)
    const size_t HB = (size_t)N * HID * sizeof(float);   // 12.8 MB
    const size_t PB = (size_t)E * 8 * sizeof(float);     // 25.6 MB packed attrs (edge order)
    const size_t SB = ((size_t)E * sizeof(int2) + 1023) & ~(size_t)1023; // 6.4 MB {src,e}

    char* ws = (char*)d_ws;
    float* h    = (float*)(ws);            // [N,64]
    float* agg  = (float*)(ws + HB);       // [N,64]
    const size_t NEEDED = 2 * HB + PB + SB + (size_t)(1 << 20);
    const bool use_csr = (ws_size >= NEEDED);

    char* meta = use_csr ? (ws + 2 * HB + PB + SB) : (ws + 2 * HB);
    float* packed = (float*)(ws + 2 * HB);           // CSR mode only (edge order)
    int2*  spos   = (int2*) (ws + 2 * HB + PB);      // CSR {src, edge id}
    int*   rowptr = (int*)(meta);                    // (N+1) ints, 200KB slot
    int*   cursor = (int*)(meta + 200 * 1024);
    int*   deg    = (int*)(meta + 400 * 1024);
    int*   bsum   = (int*)(meta + 600 * 1024);
    int*   bpre   = (int*)(meta + 601 * 1024);
    float* Wc     = (float*)(meta + 608 * 1024);     // 3*320 floats
    float* bc     = (float*)(meta + 616 * 1024);     // 3*64 floats
    float* psum   = (float*)(meta + 620 * 1024);     // 16KB
    int*   pmaxi  = (int*)(meta + 636 * 1024);       // 16KB
    int*   pcnt   = (int*)(meta + 652 * 1024);       // 256B

    // ---- one-time per call: h0, combined weights, CSR build ----
    node_embed_kernel<<<(N * HID + 255) / 256, 256, 0, stream>>>(x, node_W, node_b, h, N);
    combine_weights_kernel<<<N_LAYERS, 384, 0, stream>>>(edge_W, edge_b, lin_W, lin_b, Wc, bc);

    if (use_csr) {
        hipMemsetAsync(deg, 0, (size_t)N * sizeof(int), stream);
        hist_kernel<<<(E + 255) / 256, 256, 0, stream>>>(edge_index, deg, E);
        scan1_kernel<<<NBLK, 256, 0, stream>>>(deg, bsum, N);
        scan2_kernel<<<1, 256, 0, stream>>>(bsum, bpre, NBLK);
        scan3_kernel<<<NBLK, 256, 0, stream>>>(deg, bpre, rowptr, N, E);
        hipMemcpyAsync(cursor, rowptr, (size_t)N * sizeof(int),
                       hipMemcpyDeviceToDevice, stream);
        scatter_kernel<<<(E + 255) / 256, 256, 0, stream>>>(edge_index, edge_attr,
                                                            cursor, packed, spos, E);
    }

    // ---- layers ----
    for (int l = 0; l < N_LAYERS; ++l) {
        if (use_csr) {
            agg_kernel<<<2048, 256, 0, stream>>>(rowptr, spos, packed, h,
                                                 Wc + l * 320, bc + l * 64, agg, N);
        } else {
            hipMemsetAsync(agg, 0, HB, stream);
            edge_kernel<<<2048, 256, 0, stream>>>(edge_index, edge_attr, h,
                                                  Wc + l * 320, bc + l * 64, agg, E);
        }
        node_mlp_kernel<<<768, 256, 0, stream>>>(h, agg,
                                                 mlp_W1 + (size_t)l * HID * HID, mlp_b1 + l * HID,
                                                 mlp_W2 + (size_t)l * HID * HID, mlp_b2 + l * HID,
                                                 bn_g + l * HID, bn_b + l * HID, h, N);
    }

    // ---- pooling + head ----  (psum/pmaxi/pcnt zeroed: contiguous region)
    hipMemsetAsync(psum, 0, (636 - 620) * 1024 + 16384 + 256, stream);
    pool_kernel<<<196, 256, 0, stream>>>(h, batch, psum, pmaxi, pcnt, N);
    head_kernel<<<N_GRAPHS, 256, 0, stream>>>(psum, pmaxi, pcnt,
                                              head_W1, head_b1, head_W2, head_b2, out);
}

// Round 10
// 400.576 us; speedup vs baseline: 1.1279x; 1.1279x over previous
//
#include <hip/hip_runtime.h>
#include <hip/hip_bf16.h>

#define HID 64
#define N_LAYERS 3
#define N_GRAPHS 64
#define N_CLASSES 5
#define CHUNK 4096          // edges per partition block
#define MAXB 1024           // max buckets (N <= 262144); bucket = 256 nodes

// ---------------------------------------------------------------------------
// h0 = x @ node_W + node_b       [N,64]    (one wave per node, lane=channel)
// ---------------------------------------------------------------------------
__global__ __launch_bounds__(256) void node_embed_kernel(
    const float* __restrict__ x, const float* __restrict__ W,
    const float* __restrict__ b, float* __restrict__ h, int N)
{
    int tid = blockIdx.x * 256 + threadIdx.x;
    int n = tid >> 6;
    int c = tid & 63;
    if (n >= N) return;
    const float* xr = x + (size_t)n * 5;
    float acc = b[c];
#pragma unroll
    for (int k = 0; k < 5; ++k) acc = fmaf(xr[k], W[k * 64 + c], acc);
    h[(size_t)n * 64 + c] = acc;
}

// ---------------------------------------------------------------------------
// Wc[l] = edge_W @ lin_W[l]   [5,64];  bc[l] = edge_b @ lin_W[l] + lin_b[l]
// ---------------------------------------------------------------------------
__global__ __launch_bounds__(384) void combine_weights_kernel(
    const float* __restrict__ edge_W, const float* __restrict__ edge_b,
    const float* __restrict__ lin_W, const float* __restrict__ lin_b,
    float* __restrict__ Wc, float* __restrict__ bc)
{
    int l = blockIdx.x;
    int c = threadIdx.x & 63;
    int k = threadIdx.x >> 6;
    const float* LW = lin_W + (size_t)l * 64 * 64;
    if (k < 5) {
        float acc = 0.f;
        for (int j = 0; j < 64; ++j) acc = fmaf(edge_W[k * 64 + j], LW[j * 64 + c], acc);
        Wc[l * 320 + k * 64 + c] = acc;
    } else {
        float acc = lin_b[l * 64 + c];
        for (int j = 0; j < 64; ++j) acc = fmaf(edge_b[j], LW[j * 64 + c], acc);
        bc[l * 64 + c] = acc;
    }
}

// ===========================================================================
// CSR build v2 (once per call): LDS-staged two-phase counting sort.
// No random global scatter anywhere: phase A writes contiguous per-bucket
// runs; phase B scatters only within an L2-resident 128KB bucket region.
// ===========================================================================

// bucket histogram (bucket = dst>>8), LDS-staged
__global__ __launch_bounds__(256) void bucket_hist_kernel(
    const int* __restrict__ ei, int* __restrict__ bhist, int E, int nb)
{
    __shared__ int lh[MAXB];
    for (int i = threadIdx.x; i < nb; i += 256) lh[i] = 0;
    __syncthreads();
    int stride = gridDim.x * 256;
    for (int e = blockIdx.x * 256 + threadIdx.x; e < E; e += stride)
        atomicAdd(&lh[ei[E + e] >> 8], 1);
    __syncthreads();
    for (int i = threadIdx.x; i < nb; i += 256)
        if (lh[i]) atomicAdd(&bhist[i], lh[i]);
}

// exclusive scan of bucket hist -> boff; init bcur = boff
__global__ __launch_bounds__(1024) void bucket_scan_kernel(
    const int* __restrict__ bhist, int* __restrict__ boff, int* __restrict__ bcur,
    int nb, int E)
{
    __shared__ int s[MAXB];
    int t = threadIdx.x;
    int v = (t < nb) ? bhist[t] : 0;
    s[t] = v; __syncthreads();
    for (int off = 1; off < MAXB; off <<= 1) {
        int x = (t >= off) ? s[t - off] : 0;
        __syncthreads();
        s[t] += x;
        __syncthreads();
    }
    if (t < nb) { int ex = s[t] - v; boff[t] = ex; bcur[t] = ex; }
    if (t == 0) boff[nb] = E;
}

// Phase A: partition one 4096-edge chunk into bucket-major order.
// 32B record: {src_bits, dst_bits, a0..a4, pad}. LDS: 128KB stage + 16KB meta.
__global__ __launch_bounds__(1024) void partition_kernel(
    const int* __restrict__ ei, const float* __restrict__ ea,
    int* __restrict__ bcur, float* __restrict__ tmprec, int E, int nb)
{
    __shared__ float stage[CHUNK * 8];   // 128 KB
    __shared__ int ihist[MAXB];
    __shared__ int iscan[MAXB];
    __shared__ int cnt2[MAXB];
    __shared__ int gbase[MAXB];
    int t = threadIdx.x;                 // block = 1024 = MAXB
    int e0 = blockIdx.x * CHUNK;
    int cnt = min(CHUNK, E - e0);

    ihist[t] = 0;
    cnt2[t] = 0;
    __syncthreads();
    for (int i = t; i < cnt; i += 1024)
        atomicAdd(&ihist[ei[E + e0 + i] >> 8], 1);
    __syncthreads();
    // exclusive scan ihist -> iscan (Hillis-Steele, double-sync in-place)
    int v = ihist[t];
    iscan[t] = v; __syncthreads();
    for (int off = 1; off < MAXB; off <<= 1) {
        int x = (t >= off) ? iscan[t - off] : 0;
        __syncthreads();
        iscan[t] += x;
        __syncthreads();
    }
    iscan[t] -= v;
    // per-block global reservation (one atomic per non-empty bucket)
    gbase[t] = v ? atomicAdd(&bcur[t], v) : 0;
    __syncthreads();
    // place records into LDS stage, bucket-major
    for (int i = t; i < cnt; i += 1024) {
        int e = e0 + i;
        int src = ei[e];
        int dst = ei[E + e];
        const float* p = ea + (size_t)e * 5;
        int b = dst >> 8;
        int r = atomicAdd(&cnt2[b], 1);
        int slot = iscan[b] + r;
        float4* q = reinterpret_cast<float4*>(stage + (size_t)slot * 8);
        q[0] = make_float4(__int_as_float(src), __int_as_float(dst), p[0], p[1]);
        q[1] = make_float4(p[2], p[3], p[4], 0.f);
    }
    __syncthreads();
    // copy out: consecutive slots -> consecutive global addrs within a run
    for (int slot = t; slot < cnt; slot += 1024) {
        int lo = 0, hi = MAXB - 1;          // largest b with iscan[b] <= slot
        while (lo < hi) {
            int mid = (lo + hi + 1) >> 1;
            if (iscan[mid] <= slot) lo = mid; else hi = mid - 1;
        }
        int b = lo;
        size_t g = (size_t)gbase[b] + (size_t)(slot - iscan[b]);
        const float4* q = reinterpret_cast<const float4*>(stage + (size_t)slot * 8);
        float4 r0 = q[0], r1 = q[1];
        float4* o = reinterpret_cast<float4*>(tmprec + g * 8);
        o[0] = r0;
        o[1] = r1;
    }
}

// Phase B: per 256-node bucket, order records by node, emit rowptr + csrc +
// packed (CSR order). Scatter confined to the bucket's L2-resident region.
__global__ __launch_bounds__(256) void bucket_sort_kernel(
    const int* __restrict__ boff, const float* __restrict__ tmprec,
    int* __restrict__ rowptr, int* __restrict__ csrc, float* __restrict__ packed,
    int N, int E, int nb)
{
    __shared__ int cnt[256];
    __shared__ int loff[256];
    int g = blockIdx.x;
    int t = threadIdx.x;
    int s0 = boff[g], s1 = boff[g + 1];
    int nb0 = g << 8;
    cnt[t] = 0;
    __syncthreads();
    for (int i = s0 + t; i < s1; i += 256) {
        int dst = __float_as_int(tmprec[(size_t)i * 8 + 1]);
        atomicAdd(&cnt[dst & 255], 1);
    }
    __syncthreads();
    int v = cnt[t];
    loff[t] = v; __syncthreads();
    for (int off = 1; off < 256; off <<= 1) {
        int x = (t >= off) ? loff[t - off] : 0;
        __syncthreads();
        loff[t] += x;
        __syncthreads();
    }
    loff[t] -= v;
    __syncthreads();
    if (nb0 + t < N) rowptr[nb0 + t] = s0 + loff[t];
    if (g == nb - 1 && t == 0) rowptr[N] = E;
    cnt[t] = 0;
    __syncthreads();
    for (int i = s0 + t; i < s1; i += 256) {
        const float4* q = reinterpret_cast<const float4*>(tmprec + (size_t)i * 8);
        float4 r0 = q[0], r1 = q[1];
        int src = __float_as_int(r0.x);
        int d = __float_as_int(r0.y) & 255;
        int r = atomicAdd(&cnt[d], 1);
        size_t pos = (size_t)s0 + (size_t)loff[d] + (size_t)r;
        csrc[pos] = src;
        float4* o = reinterpret_cast<float4*>(packed + pos * 8);
        o[0] = make_float4(r0.z, r0.w, r1.x, r1.y);
        o[1] = make_float4(r1.z, 0.f, 0.f, 0.f);
    }
}

// ---------------------------------------------------------------------------
// Atomic-free aggregation (R5-proven structure): wave per node, lane=channel.
// src indices from ONE coalesced per-lane load per <=64-edge chunk, broadcast
// via __shfl; attr records now sequential in CSR order again.
// ---------------------------------------------------------------------------
__global__ __launch_bounds__(256) void agg_kernel(
    const int* __restrict__ rowptr, const int* __restrict__ csrc,
    const float* __restrict__ packed,
    const float* __restrict__ h, const float* __restrict__ Wc,
    const float* __restrict__ bc, float* __restrict__ agg, int N)
{
    int lane = threadIdx.x & 63;
    float w0 = Wc[0 * 64 + lane];
    float w1 = Wc[1 * 64 + lane];
    float w2 = Wc[2 * 64 + lane];
    float w3 = Wc[3 * 64 + lane];
    float w4 = Wc[4 * 64 + lane];
    float bb = bc[lane];

    int wid = (blockIdx.x * 256 + threadIdx.x) >> 6;
    int nw  = (gridDim.x * 256) >> 6;
    for (int n = wid; n < N; n += nw) {
        int eb = rowptr[n];
        int ee = rowptr[n + 1];
        float acc = 0.f;
        for (int base = eb; base < ee; base += 64) {
            int cnt = min(64, ee - base);
            int sv = csrc[base + min(lane, cnt - 1)];
            int j = 0;
            for (; j + 3 < cnt; j += 4) {
                int s0 = __shfl(sv, j + 0);
                int s1 = __shfl(sv, j + 1);
                int s2 = __shfl(sv, j + 2);
                int s3 = __shfl(sv, j + 3);
                float h0 = h[(size_t)s0 * 64 + lane];
                float h1 = h[(size_t)s1 * 64 + lane];
                float h2 = h[(size_t)s2 * 64 + lane];
                float h3 = h[(size_t)s3 * 64 + lane];
                const float4* q = reinterpret_cast<const float4*>(packed + (size_t)(base + j) * 8);
                float4 r0a = q[0], r0b = q[1];
                float4 r1a = q[2], r1b = q[3];
                float4 r2a = q[4], r2b = q[5];
                float4 r3a = q[6], r3b = q[7];
                float m0 = bb + h0;
                m0 = fmaf(r0a.x, w0, m0); m0 = fmaf(r0a.y, w1, m0);
                m0 = fmaf(r0a.z, w2, m0); m0 = fmaf(r0a.w, w3, m0);
                m0 = fmaf(r0b.x, w4, m0);
                float m1 = bb + h1;
                m1 = fmaf(r1a.x, w0, m1); m1 = fmaf(r1a.y, w1, m1);
                m1 = fmaf(r1a.z, w2, m1); m1 = fmaf(r1a.w, w3, m1);
                m1 = fmaf(r1b.x, w4, m1);
                float m2 = bb + h2;
                m2 = fmaf(r2a.x, w0, m2); m2 = fmaf(r2a.y, w1, m2);
                m2 = fmaf(r2a.z, w2, m2); m2 = fmaf(r2a.w, w3, m2);
                m2 = fmaf(r2b.x, w4, m2);
                float m3 = bb + h3;
                m3 = fmaf(r3a.x, w0, m3); m3 = fmaf(r3a.y, w1, m3);
                m3 = fmaf(r3a.z, w2, m3); m3 = fmaf(r3a.w, w3, m3);
                m3 = fmaf(r3b.x, w4, m3);
                acc += fmaxf(m0, 0.f);
                acc += fmaxf(m1, 0.f);
                acc += fmaxf(m2, 0.f);
                acc += fmaxf(m3, 0.f);
            }
            for (; j < cnt; ++j) {
                int s0 = __shfl(sv, j);
                float h0 = h[(size_t)s0 * 64 + lane];
                const float4* q = reinterpret_cast<const float4*>(packed + (size_t)(base + j) * 8);
                float4 r0 = q[0];
                float4 r1 = q[1];
                float m = bb + h0;
                m = fmaf(r0.x, w0, m);
                m = fmaf(r0.y, w1, m);
                m = fmaf(r0.z, w2, m);
                m = fmaf(r0.w, w3, m);
                m = fmaf(r1.x, w4, m);
                acc += fmaxf(m, 0.f);
            }
        }
        agg[(size_t)n * 64 + lane] = acc;
    }
}

// ---------------------------------------------------------------------------
// Fallback (small ws): edge-parallel scatter with atomics
// ---------------------------------------------------------------------------
__global__ __launch_bounds__(256) void edge_kernel(
    const int* __restrict__ ei, const float* __restrict__ ea,
    const float* __restrict__ h, const float* __restrict__ Wc,
    const float* __restrict__ bc, float* __restrict__ agg, int E)
{
    int lane = threadIdx.x & 63;
    float w0 = Wc[0 * 64 + lane];
    float w1 = Wc[1 * 64 + lane];
    float w2 = Wc[2 * 64 + lane];
    float w3 = Wc[3 * 64 + lane];
    float w4 = Wc[4 * 64 + lane];
    float bb = bc[lane];

    int wave   = (blockIdx.x * 256 + threadIdx.x) >> 6;
    int nwaves = (gridDim.x * 256) >> 6;
    for (int e = wave; e < E; e += nwaves) {
        int src = ei[e];
        int dst = ei[E + e];
        const float* eap = ea + (size_t)e * 5;
        float m = bb + h[(size_t)src * 64 + lane];
        m = fmaf(eap[0], w0, m);
        m = fmaf(eap[1], w1, m);
        m = fmaf(eap[2], w2, m);
        m = fmaf(eap[3], w3, m);
        m = fmaf(eap[4], w4, m);
        m = fmaxf(m, 0.f);
        atomicAdd(&agg[(size_t)dst * 64 + lane], m);
    }
}

// ---------------------------------------------------------------------------
// Node update: z = h + agg; z = relu(z@W1+b1)@W2+b2; z = bn; h = relu(z)
// ---------------------------------------------------------------------------
__global__ __launch_bounds__(256) void node_mlp_kernel(
    const float* __restrict__ h, const float* __restrict__ agg,
    const float* __restrict__ W1, const float* __restrict__ b1v,
    const float* __restrict__ W2, const float* __restrict__ b2v,
    const float* __restrict__ bng, const float* __restrict__ bnb,
    float* __restrict__ hout, int N)
{
    __shared__ float zbuf[4][64];
    int lane = threadIdx.x & 63;
    int w = threadIdx.x >> 6;

    float w1c[64], w2c[64];
#pragma unroll
    for (int k = 0; k < 64; ++k) w1c[k] = W1[k * 64 + lane];
#pragma unroll
    for (int k = 0; k < 64; ++k) w2c[k] = W2[k * 64 + lane];

    const float inv_std = 0.99999500003749981f; // 1/sqrt(1 + 1e-5)
    float bias1 = b1v[lane];
    float bias2 = b2v[lane];
    float scale = bng[lane] * inv_std;
    float shift = bnb[lane];

    int wid = blockIdx.x * 4 + w;
    int nw  = gridDim.x * 4;
    for (int n = wid; n < N; n += nw) {
        size_t off = (size_t)n * 64 + lane;
        float z = h[off] + agg[off];
        zbuf[w][lane] = z;
        float acc = bias1;
#pragma unroll
        for (int k4 = 0; k4 < 16; ++k4) {
            float4 zk = *reinterpret_cast<const float4*>(&zbuf[w][k4 * 4]);
            acc = fmaf(zk.x, w1c[k4 * 4 + 0], acc);
            acc = fmaf(zk.y, w1c[k4 * 4 + 1], acc);
            acc = fmaf(zk.z, w1c[k4 * 4 + 2], acc);
            acc = fmaf(zk.w, w1c[k4 * 4 + 3], acc);
        }
        float t = fmaxf(acc, 0.f);
        zbuf[w][lane] = t;
        float acc2 = bias2;
#pragma unroll
        for (int k4 = 0; k4 < 16; ++k4) {
            float4 tk = *reinterpret_cast<const float4*>(&zbuf[w][k4 * 4]);
            acc2 = fmaf(tk.x, w2c[k4 * 4 + 0], acc2);
            acc2 = fmaf(tk.y, w2c[k4 * 4 + 1], acc2);
            acc2 = fmaf(tk.z, w2c[k4 * 4 + 2], acc2);
            acc2 = fmaf(tk.w, w2c[k4 * 4 + 3], acc2);
        }
        float y = fmaf(acc2, scale, shift);
        hout[off] = fmaxf(y, 0.f);
    }
}

// ---------------------------------------------------------------------------
// Pooling: batch sorted -> per-wave contiguous chunk, flush on graph change.
// ---------------------------------------------------------------------------
__global__ __launch_bounds__(256) void pool_kernel(
    const float* __restrict__ h, const int* __restrict__ batch,
    float* __restrict__ psum, int* __restrict__ pmaxi, int* __restrict__ pcount, int N)
{
    int lane = threadIdx.x & 63;
    int chunks = gridDim.x * 4;
    int wid = blockIdx.x * 4 + (threadIdx.x >> 6);
    int CH = (N + chunks - 1) / chunks;
    int n0 = wid * CH;
    int n1 = min(N, n0 + CH);
    if (n0 >= n1) return;

    int gcur = batch[n0];
    float s = 0.f, mx = 0.f;
    int cnt = 0;
    for (int n = n0; n < n1; ++n) {
        int g = batch[n];
        if (g != gcur) {
            atomicAdd(&psum[gcur * 64 + lane], s);
            atomicMax(&pmaxi[gcur * 64 + lane], __float_as_int(mx));
            if (lane == 0) atomicAdd(&pcount[gcur], cnt);
            gcur = g; s = 0.f; mx = 0.f; cnt = 0;
        }
        float v = h[(size_t)n * 64 + lane];
        s += v;
        mx = fmaxf(mx, v);
        ++cnt;
    }
    atomicAdd(&psum[gcur * 64 + lane], s);
    atomicMax(&pmaxi[gcur * 64 + lane], __float_as_int(mx));
    if (lane == 0) atomicAdd(&pcount[gcur], cnt);
}

// ---------------------------------------------------------------------------
// Head: one block per graph.
// ---------------------------------------------------------------------------
__global__ __launch_bounds__(256) void head_kernel(
    const float* __restrict__ psum, const int* __restrict__ pmaxi,
    const int* __restrict__ pcount,
    const float* __restrict__ W1, const float* __restrict__ b1,
    const float* __restrict__ W2, const float* __restrict__ b2,
    float* __restrict__ out)
{
    __shared__ float hc[192];
    __shared__ float part[4][64];
    __shared__ float tbuf[64];
    int g = blockIdx.x;
    int tid = threadIdx.x;
    int lane = tid & 63;
    int w = tid >> 6;

    if (tid < 192) {
        int sec = tid >> 6;
        int c = tid & 63;
        float s = psum[g * 64 + c];
        float v;
        if (sec == 0) {
            int cn = pcount[g];
            v = s / fmaxf((float)cn, 1.f);
        } else if (sec == 1) {
            v = __int_as_float(pmaxi[g * 64 + c]);
        } else {
            v = s;
        }
        hc[sec * 64 + c] = v;
    }
    __syncthreads();

    float acc = (w == 0) ? b1[lane] : 0.f;
#pragma unroll
    for (int kk = 0; kk < 48; ++kk) {
        int k = w * 48 + kk;
        acc = fmaf(hc[k], W1[k * 64 + lane], acc);
    }
    part[w][lane] = acc;
    __syncthreads();

    if (w == 0) {
        float t = part[0][lane] + part[1][lane] + part[2][lane] + part[3][lane];
        t = fmaxf(t, 0.f);
        tbuf[lane] = t;
        if (lane < N_CLASSES) {
            float o = b2[lane];
            for (int j = 0; j < 64; ++j) o = fmaf(tbuf[j], W2[j * N_CLASSES + lane], o);
            out[g * N_CLASSES + lane] = o;
        }
    }
}

// ---------------------------------------------------------------------------
extern "C" void kernel_launch(void* const* d_in, const int* in_sizes, int n_in,
                              void* d_out, int out_size, void* d_ws, size_t ws_size,
                              hipStream_t stream)
{
    const float* x         = (const float*)d_in[0];
    const float* edge_attr = (const float*)d_in[1];
    const int*   edge_index= (const int*)  d_in[2];
    const int*   batch     = (const int*)  d_in[3];
    const float* node_W    = (const float*)d_in[4];
    const float* node_b    = (const float*)d_in[5];
    const float* edge_W    = (const float*)d_in[6];
    const float* edge_b    = (const float*)d_in[7];
    const float* lin_W     = (const float*)d_in[8];
    const float* lin_b     = (const float*)d_in[9];
    const float* mlp_W1    = (const float*)d_in[10];
    const float* mlp_b1    = (const float*)d_in[11];
    const float* mlp_W2    = (const float*)d_in[12];
    const float* mlp_b2    = (const float*)d_in[13];
    const float* bn_g      = (const float*)d_in[14];
    const float* bn_b      = (const float*)d_in[15];
    const float* head_W1   = (const float*)d_in[16];
    const float* head_b1   = (const float*)d_in[17];
    const float* head_W2   = (const float*)d_in[18];
    const float* head_b2   = (const float*)d_in[19];
    float* out = (float*)d_out;

    const int N  = in_sizes[0] / 5;       // 50000
    const int E  = in_sizes[1] / 5;       // 800000
    const int nb = (N + 255) >> 8;        // 196 buckets of 256 nodes

    const size_t HB  = (size_t)N * HID * sizeof(float);            // 12.8 MB
    const size_t PB  = (size_t)E * 8 * sizeof(float);              // 25.6 MB
    const size_t TR  = (size_t)E * 8 * sizeof(float);              // tmprec 25.6 MB
    size_t R0 = (2 * HB > TR) ? 2 * HB : TR;                        // h+agg alias tmprec
    R0 = (R0 + 4095) & ~(size_t)4095;
    const size_t SBc = (((size_t)E * sizeof(int)) + 1023) & ~(size_t)1023; // 3.2 MB

    char* ws = (char*)d_ws;
    float* h      = (float*)(ws);                 // [N,64]
    float* agg    = (float*)(ws + HB);            // [N,64]
    float* tmprec = (float*)(ws);                 // phase A records (aliases h+agg)
    float* packed = (float*)(ws + R0);            // CSR-ordered 32B attr records
    int*   csrc   = (int*)  (ws + R0 + PB);       // CSR-ordered src indices
    char*  meta   = ws + R0 + PB + SBc;
    int*   rowptr = (int*)(meta);                 // (N+1) ints (200KB slot)
    int*   boff   = (int*)(meta + 200 * 1024);    // nb+1 ints (8KB slot)
    int*   bcur   = (int*)(meta + 208 * 1024);    // nb ints
    int*   bhist  = (int*)(meta + 212 * 1024);    // nb ints
    float* Wc     = (float*)(meta + 216 * 1024);  // 3*320 floats
    float* bc     = (float*)(meta + 224 * 1024);  // 3*64 floats
    float* psum   = (float*)(meta + 228 * 1024);  // 16KB
    int*   pmaxi  = (int*)(meta + 244 * 1024);    // 16KB
    int*   pcnt   = (int*)(meta + 260 * 1024);    // 256B

    const size_t NEEDED = R0 + PB + SBc + 264 * 1024 + (1 << 20);
    const bool use_csr = (ws_size >= NEEDED) && (nb <= MAXB);

    combine_weights_kernel<<<N_LAYERS, 384, 0, stream>>>(edge_W, edge_b, lin_W, lin_b, Wc, bc);

    if (use_csr) {
        // ---- CSR build v2: hist -> scan -> partition -> per-bucket sort ----
        hipMemsetAsync(bhist, 0, (size_t)nb * sizeof(int), stream);
        bucket_hist_kernel<<<256, 256, 0, stream>>>(edge_index, bhist, E, nb);
        bucket_scan_kernel<<<1, 1024, 0, stream>>>(bhist, boff, bcur, nb, E);
        partition_kernel<<<(E + CHUNK - 1) / CHUNK, 1024, 0, stream>>>(
            edge_index, edge_attr, bcur, tmprec, E, nb);
        bucket_sort_kernel<<<nb, 256, 0, stream>>>(boff, tmprec, rowptr, csrc,
                                                   packed, N, E, nb);
    }

    // h0 AFTER the build (h aliases tmprec)
    node_embed_kernel<<<(N * HID + 255) / 256, 256, 0, stream>>>(x, node_W, node_b, h, N);

    // ---- layers ----
    for (int l = 0; l < N_LAYERS; ++l) {
        if (use_csr) {
            agg_kernel<<<2048, 256, 0, stream>>>(rowptr, csrc, packed, h,
                                                 Wc + l * 320, bc + l * 64, agg, N);
        } else {
            hipMemsetAsync(agg, 0, HB, stream);
            edge_kernel<<<2048, 256, 0, stream>>>(edge_index, edge_attr, h,
                                                  Wc + l * 320, bc + l * 64, agg, E);
        }
        node_mlp_kernel<<<768, 256, 0, stream>>>(h, agg,
                                                 mlp_W1 + (size_t)l * HID * HID, mlp_b1 + l * HID,
                                                 mlp_W2 + (size_t)l * HID * HID, mlp_b2 + l * HID,
                                                 bn_g + l * HID, bn_b + l * HID, h, N);
    }

    // ---- pooling + head ----  (psum/pmaxi/pcnt zeroed: contiguous region)
    hipMemsetAsync(psum, 0, 16 * 1024 + 16 * 1024 + 256, stream);
    pool_kernel<<<196, 256, 0, stream>>>(h, batch, psum, pmaxi, pcnt, N);
    head_kernel<<<N_GRAPHS, 256, 0, stream>>>(psum, pmaxi, pcnt,
                                              head_W1, head_b1, head_W2, head_b2, out);
}